// Round 3
// baseline (3613.923 us; speedup 1.0000x reference)
//
#include <hip/hip_runtime.h>
#include <math.h>

#define T 64
#define H 256

typedef _Float16 f16;
typedef _Float16 f16x8 __attribute__((ext_vector_type(8)));
typedef float f32x4 __attribute__((ext_vector_type(4)));

__device__ __forceinline__ float sigm(float x) { return 1.f / (1.f + __expf(-x)); }
__device__ __forceinline__ float ftanh(float x) { return 1.f - 2.f / (__expf(2.f * x) + 1.f); }

// grid barrier: monotonic counter, release add + acquire spin (agent scope).
__device__ __forceinline__ void gridbar(unsigned* bar, unsigned target) {
  __threadfence();
  __syncthreads();
  if (threadIdx.x == 0) {
    __hip_atomic_fetch_add(bar, 1u, __ATOMIC_ACQ_REL, __HIP_MEMORY_SCOPE_AGENT);
    while (__hip_atomic_load(bar, __ATOMIC_ACQUIRE, __HIP_MEMORY_SCOPE_AGENT) < target)
      __builtin_amdgcn_s_sleep(1);
    __threadfence();
  }
  __syncthreads();
}

// ---------------------------------------------------------------------------
// k_prep_u: B-fragment ordering for the 65 scan LSTMs (64 feature + Y).
// Element (lstm, slice, g, kt, lane, e) = U[k = kt*32+(lane>>4)*8+e]
//                                          [col = g*256 + slice*16 + (lane&15)]
// ---------------------------------------------------------------------------
__global__ __launch_bounds__(512) void k_prep_u(
    const float* __restrict__ Uxp, const float* __restrict__ Uxn,
    const float* __restrict__ Uy, f16* __restrict__ Uf2)
{
  const int unit = blockIdx.x;           // lstm*16 + slice
  const int lstm = unit >> 4, slice = unit & 15;
  const float* src = (lstm < 32) ? (Uxp + (size_t)lstm * 262144)
                   : (lstm < 64) ? (Uxn + (size_t)(lstm - 32) * 262144)
                   : Uy;
  for (int fl = threadIdx.x; fl < 2048; fl += 512) {
    const int g = fl >> 9, kt = (fl >> 6) & 7, l = fl & 63;
    const int col = g * 256 + slice * 16 + (l & 15);
    const int k0 = kt * 32 + (l >> 4) * 8;
    f16x8 v;
    #pragma unroll
    for (int e = 0; e < 8; ++e) v[e] = (f16)src[(size_t)(k0 + e) * 1024 + col];
    *(f16x8*)(Uf2 + (((size_t)unit * 32 + g * 8 + kt) * 512) + (size_t)l * 8) = v;
  }
}

// ---------------------------------------------------------------------------
// k_prep_umi: B-fragments for the MI-LSTM. slot 0-3 = Um gates, 4-5 = Upa
// (ip,cp), 6-7 = Una (in,cn), 8 = Wa. Per (blk 0..15, slot): 16-col ntile.
// ---------------------------------------------------------------------------
__global__ __launch_bounds__(512) void k_prep_umi(
    const float* __restrict__ Um, const float* __restrict__ Upa,
    const float* __restrict__ Una, const float* __restrict__ Wa,
    f16* __restrict__ Ufmi)
{
  const int blk = blockIdx.x / 9, slot = blockIdx.x % 9;
  const int kt = threadIdx.x >> 6, l = threadIdx.x & 63;
  const int n = blk * 16 + (l & 15);
  const int k0 = kt * 32 + (l >> 4) * 8;
  const float* src; int col, ld;
  if (slot < 4)      { src = Um;  col = slot * 256 + n;       ld = 1024; }
  else if (slot < 6) { src = Upa; col = (slot - 4) * 256 + n; ld = 512;  }
  else if (slot < 8) { src = Una; col = (slot - 6) * 256 + n; ld = 512;  }
  else               { src = Wa;  col = n;                    ld = 256;  }
  f16x8 v;
  #pragma unroll
  for (int e = 0; e < 8; ++e) v[e] = (f16)src[(size_t)(k0 + e) * ld + col];
  *(f16x8*)(Ufmi + (((size_t)blk * 9 + slot) * 8 + kt) * 512 + (size_t)l * 8) = v;
}

// ---------------------------------------------------------------------------
// k_prep_x: X[b][t][f] -> Xt[s][f][t][b]  (coalesced float4 reads in k_scan)
// ---------------------------------------------------------------------------
__global__ __launch_bounds__(512) void k_prep_x(
    const float* __restrict__ Xp, const float* __restrict__ Xn, float* __restrict__ Xt)
{
  const int s = blockIdx.x >> 5, f = blockIdx.x & 31;
  const float* X = s ? Xn : Xp;
  for (int i = threadIdx.x; i < 2048; i += 512) {
    const int t = i >> 5, b = i & 31;
    Xt[((size_t)(s * 32 + f) * 64 + t) * 32 + b] = X[((size_t)b * 64 + t) * 32 + f];
  }
}

// ---------------------------------------------------------------------------
// k_prep_yg0: yg0t[t][col][b] = Y[b,t,:] @ Wy + by
// ---------------------------------------------------------------------------
__global__ __launch_bounds__(1024) void k_prep_yg0(
    const float* __restrict__ Y, const float* __restrict__ Wy,
    const float* __restrict__ by, float* __restrict__ yg0t)
{
  const int t = blockIdx.x, col = threadIdx.x;
  float wv[10];
  #pragma unroll
  for (int i = 0; i < 10; ++i) wv[i] = Wy[i * 1024 + col];
  const float bv = by[col];
  for (int b = 0; b < 32; ++b) {
    float a = bv;
    #pragma unroll
    for (int i = 0; i < 10; ++i) a += Y[((size_t)b * 64 + t) * 10 + i] * wv[i];
    yg0t[((size_t)t * 1024 + col) * 32 + b] = a;
  }
}

// ---------------------------------------------------------------------------
// k_scan: cooperative scan of 65 LSTMs (64 feature + Y), 130 blocks = 2 per
// LSTM (column halves), 8 waves each. Wave = 16-n-slice x 4 gates, U frags
// in registers (128 VGPR). h exchanged via double-buffered global f16 with a
// per-LSTM pair barrier; staged to XOR-swizzled LDS for A-fragments.
// ---------------------------------------------------------------------------
__global__ __launch_bounds__(512, 2) void k_scan(
    const float* __restrict__ Xt,
    const float* __restrict__ Wxp, const float* __restrict__ bxp,
    const float* __restrict__ Wxn, const float* __restrict__ bxn,
    const f16* __restrict__ Uf2, const float* __restrict__ yg0t,
    f16* __restrict__ hg, float* __restrict__ Yh,
    float* __restrict__ Ph, float* __restrict__ Nh, unsigned* __restrict__ bars)
{
  __shared__ __align__(16) f16 hs[32 * 256];  // 16 KB, XOR-swizzled
  const int tid = threadIdx.x;
  const int w = tid >> 6, l = tid & 63;
  const int cl = l & 15, lq = l >> 4;
  const int bid = blockIdx.x;
  const int lstm = bid >> 1, half = bid & 1;
  const int slice = half * 8 + w;
  const int n = slice * 16 + cl;
  const bool isY = (lstm == 64);
  const int s = (lstm >= 32) ? 1 : 0;
  const int f = lstm & 31;

  f16x8 U[4][8];
  {
    const f16* ub = Uf2 + ((size_t)(lstm * 16 + slice) * 32) * 512 + (size_t)l * 8;
    #pragma unroll
    for (int g = 0; g < 4; ++g)
      #pragma unroll
      for (int kt = 0; kt < 8; ++kt)
        U[g][kt] = *(const f16x8*)(ub + (size_t)(g * 8 + kt) * 512);
  }

  float Wc[4], Bc[4];
  const float* xrow = nullptr;
  if (!isY) {
    const float* Wf = (s ? Wxn : Wxp) + (size_t)f * 1024;
    const float* bf = (s ? bxn : bxp) + (size_t)f * 1024;
    #pragma unroll
    for (int g = 0; g < 4; ++g) { Wc[g] = Wf[g * 256 + n]; Bc[g] = bf[g * 256 + n]; }
    xrow = Xt + (size_t)(s * 32 + f) * 64 * 32;
  }
  float* Acc = s ? Nh : Ph;
  unsigned* bar = bars + lstm * 32;

  float c[2][4] = {{0.f, 0.f, 0.f, 0.f}, {0.f, 0.f, 0.f, 0.f}};

  for (int t = 0; t < T; ++t) {
    // stage hg[t&1][lstm] -> swizzled LDS (16-B chunks keep alignment)
    {
      const uint4* src = (const uint4*)(hg + ((size_t)(t & 1) * 65 + lstm) * 8192);
      #pragma unroll
      for (int i = 0; i < 2; ++i) {
        const int idx4 = tid * 2 + i;
        const uint4 v = src[idx4];
        const int byte = idx4 * 16;
        const int b = byte >> 9, kb = byte & 511;
        *(uint4*)((char*)hs + b * 512 + (kb ^ ((b & 7) << 4))) = v;
      }
    }
    __syncthreads();

    f32x4 acc[4][2];
    #pragma unroll
    for (int g = 0; g < 4; ++g) { acc[g][0] = f32x4{0,0,0,0}; acc[g][1] = f32x4{0,0,0,0}; }
    #pragma unroll
    for (int mt = 0; mt < 2; ++mt) {
      f16x8 a8[8];
      const int row = 16 * mt + cl;
      #pragma unroll
      for (int kt = 0; kt < 8; ++kt)
        a8[kt] = *(const f16x8*)((char*)hs + row * 512 + ((kt * 64 + lq * 16) ^ ((cl & 7) << 4)));
      #pragma unroll
      for (int kt = 0; kt < 8; ++kt)
        #pragma unroll
        for (int g = 0; g < 4; ++g)
          acc[g][mt] = __builtin_amdgcn_mfma_f32_16x16x32_f16(a8[kt], U[g][kt], acc[g][mt], 0, 0, 0);
    }

    f16* dst = hg + ((size_t)((t + 1) & 1) * 65 + lstm) * 8192;
    #pragma unroll
    for (int mt = 0; mt < 2; ++mt) {
      float4 xv; float4 yv[4];
      if (!isY) xv = *(const float4*)(xrow + t * 32 + 16 * mt + lq * 4);
      else {
        #pragma unroll
        for (int g = 0; g < 4; ++g)
          yv[g] = *(const float4*)(yg0t + ((size_t)t * 1024 + g * 256 + n) * 32 + 16 * mt + lq * 4);
      }
      const float* xp = (const float*)&xv;
      #pragma unroll
      for (int j = 0; j < 4; ++j) {
        const int b = 16 * mt + lq * 4 + j;
        float p0, p1, p2, p3;
        if (!isY) {
          const float x = xp[j];
          p0 = acc[0][mt][j] + x * Wc[0] + Bc[0];
          p1 = acc[1][mt][j] + x * Wc[1] + Bc[1];
          p2 = acc[2][mt][j] + x * Wc[2] + Bc[2];
          p3 = acc[3][mt][j] + x * Wc[3] + Bc[3];
        } else {
          p0 = acc[0][mt][j] + ((const float*)&yv[0])[j];
          p1 = acc[1][mt][j] + ((const float*)&yv[1])[j];
          p2 = acc[2][mt][j] + ((const float*)&yv[2])[j];
          p3 = acc[3][mt][j] + ((const float*)&yv[3])[j];
        }
        const float ig = sigm(p0), fg = sigm(p1), gy = ftanh(p2), og = sigm(p3);
        c[mt][j] = fg * c[mt][j] + ig * gy;
        const float h = og * ftanh(c[mt][j]);
        dst[b * 256 + n] = (f16)h;
        if (!isY) atomicAdd(&Acc[((size_t)b * T + t) * H + n], h * 0.03125f);
        else Yh[((size_t)b * T + t) * H + n] = h;
      }
    }
    if (t < T - 1) gridbar(bar, 2u * (unsigned)(t + 1));
  }
}

// ---------------------------------------------------------------------------
// k_xg: MI-LSTM input projections (unchanged structure).
// ---------------------------------------------------------------------------
__global__ __launch_bounds__(1024) void k_xg(
    const float* __restrict__ Yh, const float* __restrict__ Ph, const float* __restrict__ Nh,
    const float* __restrict__ Wm, const float* __restrict__ bm,
    const float* __restrict__ Wpa, const float* __restrict__ bpa,
    const float* __restrict__ Wna, const float* __restrict__ bna,
    float* __restrict__ yg, float* __restrict__ pg, float* __restrict__ ng)
{
  __shared__ __align__(16) float A[8][768];
  const int tid = threadIdx.x;
  const int ro  = blockIdx.x * 8;

  for (int idx = tid; idx < 8 * 768; idx += 1024) {
    const int r = idx / 768, cc = idx % 768;
    const int row = ro + r;
    float v;
    if (cc < 256)      v = Yh[(size_t)row * H + cc];
    else if (cc < 512) v = Ph[(size_t)row * H + (cc - 256)];
    else               v = Nh[(size_t)row * H + (cc - 512)];
    A[r][cc] = v;
  }
  __syncthreads();

  float acc[8];
  #pragma unroll
  for (int r = 0; r < 8; ++r) acc[r] = bm[tid];
  for (int k = 0; k < H; k += 4) {
    const float w0 = Wm[(k + 0) * 1024 + tid];
    const float w1 = Wm[(k + 1) * 1024 + tid];
    const float w2 = Wm[(k + 2) * 1024 + tid];
    const float w3 = Wm[(k + 3) * 1024 + tid];
    #pragma unroll
    for (int r = 0; r < 8; ++r) {
      const float4 av = *(const float4*)&A[r][k];
      acc[r] += w0 * av.x + w1 * av.y + w2 * av.z + w3 * av.w;
    }
  }
  #pragma unroll
  for (int r = 0; r < 8; ++r) yg[(size_t)(ro + r) * 1024 + tid] = acc[r];

  const int col = tid & 511;
  const float* Wx = (tid < 512) ? Wpa : Wna;
  const float* bx = (tid < 512) ? bpa : bna;
  float* outp     = (tid < 512) ? pg : ng;
  const int aoff  = (tid < 512) ? 256 : 512;
  #pragma unroll
  for (int r = 0; r < 8; ++r) acc[r] = bx[col];
  for (int k = 0; k < H; k += 4) {
    const float w0 = Wx[(k + 0) * 512 + col];
    const float w1 = Wx[(k + 1) * 512 + col];
    const float w2 = Wx[(k + 2) * 512 + col];
    const float w3 = Wx[(k + 3) * 512 + col];
    #pragma unroll
    for (int r = 0; r < 8; ++r) {
      const float4 av = *(const float4*)&A[r][aoff + k];
      acc[r] += w0 * av.x + w1 * av.y + w2 * av.z + w3 * av.w;
    }
  }
  #pragma unroll
  for (int r = 0; r < 8; ++r) outp[(size_t)(ro + r) * 512 + col] = acc[r];
}

// ---------------------------------------------------------------------------
// k_mi: cooperative MI-LSTM. 16 blocks x 9 waves; wave = matrix slot with
// register-resident B-fragments. 2 grid barriers per step; c in registers.
// ---------------------------------------------------------------------------
__global__ __launch_bounds__(576) void k_mi(
    const float* __restrict__ yg, const float* __restrict__ pg, const float* __restrict__ ng,
    const f16* __restrict__ Ufmi, const float* __restrict__ ba,
    f16* __restrict__ Hh, f16* __restrict__ Hc, float* __restrict__ Spart,
    unsigned* __restrict__ bar, float* __restrict__ Hm)
{
  __shared__ float g_lds[9][32][16];
  const int tid = threadIdx.x;
  const int w = tid >> 6, l = tid & 63;
  const int cl = l & 15, lq = l >> 4;
  const int blk = blockIdx.x;

  f16x8 U[8];
  #pragma unroll
  for (int kt = 0; kt < 8; ++kt)
    U[kt] = *(const f16x8*)(Ufmi + (((size_t)blk * 9 + w) * 8 + kt) * 512 + (size_t)l * 8);

  const int b2 = tid >> 4, nl = tid & 15;   // state mapping (tid < 512)
  const int n2 = blk * 16 + nl;
  const float bav = ba[n2];
  float creg = 0.f;
  unsigned cnt = 0;

  for (int t = 0; t < T; ++t) {
    float pre[8];
    if (tid < 512) {
      const size_t row = (size_t)b2 * T + t;
      #pragma unroll
      for (int g = 0; g < 4; ++g) pre[g] = yg[row * 1024 + g * 256 + n2];
      pre[4] = pg[row * 512 + n2];       pre[5] = pg[row * 512 + 256 + n2];
      pre[6] = ng[row * 512 + n2];       pre[7] = ng[row * 512 + 256 + n2];
    }
    const f16* asrc = (w == 8) ? Hc : Hh;
    f32x4 acc[2] = {f32x4{0,0,0,0}, f32x4{0,0,0,0}};
    #pragma unroll
    for (int mt = 0; mt < 2; ++mt) {
      f16x8 a8[8];
      #pragma unroll
      for (int kt = 0; kt < 8; ++kt)
        a8[kt] = *(const f16x8*)(asrc + (16 * mt + cl) * 256 + kt * 32 + lq * 8);
      #pragma unroll
      for (int kt = 0; kt < 8; ++kt)
        acc[mt] = __builtin_amdgcn_mfma_f32_16x16x32_f16(a8[kt], U[kt], acc[mt], 0, 0, 0);
    }
    #pragma unroll
    for (int mt = 0; mt < 2; ++mt)
      #pragma unroll
      for (int j = 0; j < 4; ++j)
        g_lds[w][lq * 4 + j + 16 * mt][cl] = acc[mt][j];
    __syncthreads();

    float l0 = 0.f, l1 = 0.f, l2 = 0.f, fg = 0.f, og = 0.f;
    if (tid < 512) {
      const float gi = sigm(g_lds[0][b2][nl] + pre[0]);
      fg             = sigm(g_lds[1][b2][nl] + pre[1]);
      const float gy = ftanh(g_lds[2][b2][nl] + pre[2]);
      og             = sigm(g_lds[3][b2][nl] + pre[3]);
      const float ip = sigm(g_lds[4][b2][nl] + pre[4]);
      const float cp = ftanh(g_lds[5][b2][nl] + pre[5]);
      const float in = sigm(g_lds[6][b2][nl] + pre[6]);
      const float cn = ftanh(g_lds[7][b2][nl] + pre[7]);
      const float att = ftanh(g_lds[8][b2][nl] + bav);
      l0 = gi * gy; l1 = ip * cp; l2 = in * cn;
      float v0 = l0 * att, v1 = l1 * att, v2 = l2 * att;
      #pragma unroll
      for (int off = 1; off < 16; off <<= 1) {
        v0 += __shfl_xor(v0, off);
        v1 += __shfl_xor(v1, off);
        v2 += __shfl_xor(v2, off);
      }
      if (nl == 0) {
        float* sp = Spart + ((size_t)t * 32 + b2) * 48 + blk;
        sp[0] = v0; sp[16] = v1; sp[32] = v2;
      }
    }
    ++cnt; gridbar(bar, 16u * cnt);
    if (tid < 512) {
      float sv = 0.f;
      if (nl < 3) {
        const float* sp = Spart + ((size_t)t * 32 + b2) * 48 + nl * 16;
        #pragma unroll
        for (int q = 0; q < 16; ++q) sv += sp[q];
      }
      const int base = l & 0x30;
      const float s0 = __shfl(sv, base | 0);
      const float s1 = __shfl(sv, base | 1);
      const float s2 = __shfl(sv, base | 2);
      const float m = fmaxf(s0, fmaxf(s1, s2));
      const float e0 = __expf(s0 - m), e1 = __expf(s1 - m), e2 = __expf(s2 - m);
      const float lt = (e0 * l0 + e1 * l1 + e2 * l2) / (e0 + e1 + e2);
      creg = fg * creg + lt;
      const float h = og * ftanh(creg);
      Hh[b2 * 256 + n2] = (f16)h;
      Hc[b2 * 256 + n2] = (f16)creg;
      Hm[((size_t)b2 * T + t) * H + n2] = h;
    }
    if (t < T - 1) { ++cnt; gridbar(bar, 16u * cnt); }
  }
}

// ---------------------------------------------------------------------------
// k_att: temporal additive attention + linear head (unchanged).
// ---------------------------------------------------------------------------
__global__ __launch_bounds__(256) void k_att(
    const float* __restrict__ Hm, const float* __restrict__ Watt, const float* __restrict__ batt,
    const float* __restrict__ vatt, const float* __restrict__ Wlin, const float* __restrict__ blin,
    float* __restrict__ out)
{
  __shared__ __align__(16) float hm8[8][H];
  __shared__ float vred[8][4];
  __shared__ float s_lds[T];
  __shared__ float alpha_lds[T];
  __shared__ float red4[4];
  const int n = threadIdx.x;
  const int b = blockIdx.x;
  const float bn = batt[n], vn = vatt[n];

  for (int t0 = 0; t0 < T; t0 += 8) {
    __syncthreads();
    #pragma unroll
    for (int r = 0; r < 8; ++r) hm8[r][n] = Hm[((size_t)b * T + t0 + r) * H + n];
    __syncthreads();
    float acc[8];
    #pragma unroll
    for (int r = 0; r < 8; ++r) acc[r] = bn;
    for (int k = 0; k < H; k += 4) {
      const float w0 = Watt[(k + 0) * H + n];
      const float w1 = Watt[(k + 1) * H + n];
      const float w2 = Watt[(k + 2) * H + n];
      const float w3 = Watt[(k + 3) * H + n];
      #pragma unroll
      for (int r = 0; r < 8; ++r) {
        const float4 hv = *(const float4*)&hm8[r][k];
        acc[r] += w0 * hv.x + w1 * hv.y + w2 * hv.z + w3 * hv.w;
      }
    }
    #pragma unroll
    for (int r = 0; r < 8; ++r) {
      float v = tanhf(acc[r]) * vn;
      for (int off = 32; off; off >>= 1) v += __shfl_down(v, off);
      if ((n & 63) == 0) vred[r][n >> 6] = v;
    }
    __syncthreads();
    if (n < 8) s_lds[t0 + n] = vred[n][0] + vred[n][1] + vred[n][2] + vred[n][3];
  }
  __syncthreads();

  if (n < T) {
    const float sv = s_lds[n];
    float m = sv;
    for (int off = 32; off; off >>= 1) m = fmaxf(m, __shfl_xor(m, off));
    const float e = expf(sv - m);
    float sum = e;
    for (int off = 32; off; off >>= 1) sum += __shfl_xor(sum, off);
    alpha_lds[n] = e / sum;
  }
  __syncthreads();

  float acc = 0.f;
  for (int t = 0; t < T; ++t) acc += alpha_lds[t] * Hm[((size_t)b * T + t) * H + n];
  float p = acc * Wlin[n];
  for (int off = 32; off; off >>= 1) p += __shfl_down(p, off);
  if ((n & 63) == 0) red4[n >> 6] = p;
  __syncthreads();
  if (n == 0) out[b] = fmaxf(red4[0] + red4[1] + red4[2] + red4[3] + blin[0], 0.f);
}

// ---------------------------------------------------------------------------
extern "C" void kernel_launch(void* const* d_in, const int* in_sizes, int n_in,
                              void* d_out, int out_size, void* d_ws, size_t ws_size,
                              hipStream_t stream) {
  const float* Yin  = (const float*)d_in[0];
  const float* Xp   = (const float*)d_in[1];
  const float* Xn   = (const float*)d_in[2];
  const float* Wy   = (const float*)d_in[3];
  const float* Uy   = (const float*)d_in[4];
  const float* by   = (const float*)d_in[5];
  const float* Wxp  = (const float*)d_in[6];
  const float* Uxp  = (const float*)d_in[7];
  const float* bxp  = (const float*)d_in[8];
  const float* Wxn  = (const float*)d_in[9];
  const float* Uxn  = (const float*)d_in[10];
  const float* bxn  = (const float*)d_in[11];
  const float* Wm   = (const float*)d_in[12];
  const float* Um   = (const float*)d_in[13];
  const float* bm   = (const float*)d_in[14];
  const float* Wpa  = (const float*)d_in[15];
  const float* Upa  = (const float*)d_in[16];
  const float* bpa  = (const float*)d_in[17];
  const float* Wna  = (const float*)d_in[18];
  const float* Una  = (const float*)d_in[19];
  const float* bna  = (const float*)d_in[20];
  const float* Wa   = (const float*)d_in[21];
  const float* ba   = (const float*)d_in[22];
  const float* Watt = (const float*)d_in[23];
  const float* batt = (const float*)d_in[24];
  const float* vatt = (const float*)d_in[25];
  const float* Wlin = (const float*)d_in[26];
  const float* blin = (const float*)d_in[27];

  float* ws = (float*)d_ws;
  float*    Yh    = ws;                    // 524288
  float*    Ph    = ws + 524288;           // 524288
  float*    Nh    = ws + 1048576;          // 524288
  float*    Hm    = ws + 1572864;          // 524288
  float*    yg    = ws + 2097152;          // 2097152
  float*    pg    = ws + 4194304;          // 1048576
  float*    ng    = ws + 5242880;          // 1048576
  float*    yg0t  = ws + 6291456;          // 2097152
  float*    Xt    = ws + 8388608;          // 131072
  f16*      Uf2   = (f16*)(ws + 8519680);  // 17039360 f16
  f16*      Ufmi  = (f16*)(ws + 17039360); // 589824 f16
  f16*      hg    = (f16*)(ws + 17334272); // 1064960 f16 (2 x 65 x 8192)
  f16*      Hh    = (f16*)(ws + 17866752); // 8192 f16
  f16*      Hc    = (f16*)(ws + 17870848); // 8192 f16
  float*    Spart = ws + 17874944;         // 98304
  unsigned* bars  = (unsigned*)(ws + 17973248); // 2112 u32
  float*    out   = (float*)d_out;

  hipMemsetAsync(Ph,   0, (size_t)2 * 524288 * sizeof(float), stream); // Ph+Nh
  hipMemsetAsync(hg,   0, (size_t)1064960 * sizeof(f16), stream);
  hipMemsetAsync(Hh,   0, (size_t)2 * 8192 * sizeof(f16), stream);     // Hh+Hc
  hipMemsetAsync(bars, 0, (size_t)2112 * sizeof(unsigned), stream);

  k_prep_u   <<<1040, 512, 0, stream>>>(Uxp, Uxn, Uy, Uf2);
  k_prep_umi <<<144, 512, 0, stream>>>(Um, Upa, Una, Wa, Ufmi);
  k_prep_x   <<<64, 512, 0, stream>>>(Xp, Xn, Xt);
  k_prep_yg0 <<<64, 1024, 0, stream>>>(Yin, Wy, by, yg0t);

  k_scan<<<130, 512, 0, stream>>>(Xt, Wxp, bxp, Wxn, bxn, Uf2, yg0t,
                                  hg, Yh, Ph, Nh, bars);
  k_xg  <<<256, 1024, 0, stream>>>(Yh, Ph, Nh, Wm, bm, Wpa, bpa, Wna, bna, yg, pg, ng);
  k_mi  <<<16, 576, 0, stream>>>(yg, pg, ng, Ufmi, ba, Hh, Hc, Spart, bars + 2080, Hm);
  k_att <<<32, 256, 0, stream>>>(Hm, Watt, batt, vatt, Wlin, blin, out);
}